// Round 1
// baseline (536.974 us; speedup 1.0000x reference)
//
#include <hip/hip_runtime.h>
#include <cmath>

constexpr int S_LEN = 2048;
constexpr int TPB   = 256;
constexpr float EPS = 1e-8f;

__device__ __forceinline__ float fin(float v) { return isfinite(v) ? v : 0.0f; }

__global__ __launch_bounds__(TPB) void stat_feat_kernel(
    const float* __restrict__ x,
    const float* __restrict__ W1, const float* __restrict__ b1,
    const float* __restrict__ W2, const float* __restrict__ b2,
    float* __restrict__ out)
{
    __shared__ float row[S_LEN];
    __shared__ float sbuf[S_LEN];
    __shared__ float red[11][4];
    __shared__ float redB[3][4];
    __shared__ float sc[4];
    __shared__ float feats[20];
    __shared__ float hbuf[64];

    const int tid  = threadIdx.x;
    const int lane = tid & 63;
    const int wv   = tid >> 6;
    const size_t rowi = blockIdx.x;

    // ---- load row: 8 contiguous floats per thread (2x float4) ----
    const float* xr = x + rowi * S_LEN;
    float4 a0 = reinterpret_cast<const float4*>(xr)[2 * tid];
    float4 a1 = reinterpret_cast<const float4*>(xr)[2 * tid + 1];
    float r0[8] = {a0.x, a0.y, a0.z, a0.w, a1.x, a1.y, a1.z, a1.w};
    reinterpret_cast<float4*>(row)[2 * tid]     = a0;
    reinterpret_cast<float4*>(row)[2 * tid + 1] = a1;
    __syncthreads();

    // ---- phase A: mean-independent accumulators ----
    float s1 = 0.f, s2 = 0.f, sd2 = 0.f, sad = 0.f;
    float p1 = 0.f, p7 = 0.f, p24 = 0.f, se1 = 0.f, se2 = 0.f;
    float mn = r0[0], mx = r0[0];
    const int base = tid * 8;
    #pragma unroll
    for (int e = 0; e < 8; e++) {
        float v = r0[e];
        int i = base + e;
        s1 += v; s2 += v * v;
        mn = fminf(mn, v); mx = fmaxf(mx, v);
        if (i % 24 == 0) { se1 += v; se2 += v * v; }
        if (i < S_LEN - 1) {
            float nx = row[i + 1];
            float d = nx - v;
            sd2 += d * d; sad += fabsf(d); p1 += v * nx;
        }
        if (i < S_LEN - 7)  p7  += v * row[i + 7];
        if (i < S_LEN - 24) p24 += v * row[i + 24];
    }
    #pragma unroll
    for (int o = 32; o > 0; o >>= 1) {
        s1  += __shfl_down(s1,  o, 64);  s2  += __shfl_down(s2,  o, 64);
        sd2 += __shfl_down(sd2, o, 64);  sad += __shfl_down(sad, o, 64);
        p1  += __shfl_down(p1,  o, 64);  p7  += __shfl_down(p7,  o, 64);
        p24 += __shfl_down(p24, o, 64);
        se1 += __shfl_down(se1, o, 64);  se2 += __shfl_down(se2, o, 64);
        mn = fminf(mn, __shfl_down(mn, o, 64));
        mx = fmaxf(mx, __shfl_down(mx, o, 64));
    }
    if (lane == 0) {
        red[0][wv] = s1;  red[1][wv] = s2;  red[2][wv] = sd2; red[3][wv] = sad;
        red[4][wv] = p1;  red[5][wv] = p7;  red[6][wv] = p24;
        red[7][wv] = se1; red[8][wv] = se2;
        red[9][wv] = mn;  red[10][wv] = mx;
    }
    __syncthreads();
    if (tid == 0) {
        float t = red[0][0] + red[0][1] + red[0][2] + red[0][3];
        sc[0] = t * (1.0f / S_LEN);
    }
    __syncthreads();

    // ---- phase B: central moments (two-pass for accuracy) ----
    const float mean = sc[0];
    float c2 = 0.f, c3 = 0.f, c4 = 0.f;
    #pragma unroll
    for (int e = 0; e < 8; e++) {
        float xc = r0[e] - mean;
        float q = xc * xc;
        c2 += q; c3 += q * xc; c4 += q * q;
    }
    #pragma unroll
    for (int o = 32; o > 0; o >>= 1) {
        c2 += __shfl_down(c2, o, 64);
        c3 += __shfl_down(c3, o, 64);
        c4 += __shfl_down(c4, o, 64);
    }
    if (lane == 0) { redB[0][wv] = c2; redB[1][wv] = c3; redB[2][wv] = c4; }
    // (read by thread 0 only after the sort's barriers)

    // ---- bitonic sort of a copy (hybrid: in-register + LDS substages) ----
    {
        float v[8];
        #pragma unroll
        for (int e = 0; e < 8; e++) v[e] = r0[e];
        auto cw = [](float& a, float& b, bool asc) {
            float lo = fminf(a, b), hi = fmaxf(a, b);
            a = asc ? lo : hi; b = asc ? hi : lo;
        };
        // k=2
        cw(v[0],v[1],true);  cw(v[2],v[3],false); cw(v[4],v[5],true);  cw(v[6],v[7],false);
        // k=4
        cw(v[0],v[2],true);  cw(v[1],v[3],true);  cw(v[4],v[6],false); cw(v[5],v[7],false);
        cw(v[0],v[1],true);  cw(v[2],v[3],true);  cw(v[4],v[5],false); cw(v[6],v[7],false);
        // k=8 (direction uniform per thread)
        bool a8 = ((tid & 1) == 0);
        cw(v[0],v[4],a8); cw(v[1],v[5],a8); cw(v[2],v[6],a8); cw(v[3],v[7],a8);
        cw(v[0],v[2],a8); cw(v[1],v[3],a8); cw(v[4],v[6],a8); cw(v[5],v[7],a8);
        cw(v[0],v[1],a8); cw(v[2],v[3],a8); cw(v[4],v[5],a8); cw(v[6],v[7],a8);
        reinterpret_cast<float4*>(sbuf)[2 * tid]     = make_float4(v[0], v[1], v[2], v[3]);
        reinterpret_cast<float4*>(sbuf)[2 * tid + 1] = make_float4(v[4], v[5], v[6], v[7]);

        for (int k = 16; k <= S_LEN; k <<= 1) {
            __syncthreads();
            for (int j = k >> 1; j >= 8; j >>= 1) {
                #pragma unroll
                for (int u = 0; u < 4; u++) {
                    int t2 = tid + u * 256;               // 1024 pairs
                    int i = ((t2 & ~(j - 1)) << 1) | (t2 & (j - 1));
                    bool asc = ((i & k) == 0);
                    float a = sbuf[i], b = sbuf[i + j];
                    float lo = fminf(a, b), hi = fmaxf(a, b);
                    sbuf[i]     = asc ? lo : hi;
                    sbuf[i + j] = asc ? hi : lo;
                }
                __syncthreads();
            }
            // j = 4,2,1 within each thread's contiguous 8 elements
            float4 w0 = reinterpret_cast<float4*>(sbuf)[2 * tid];
            float4 w1 = reinterpret_cast<float4*>(sbuf)[2 * tid + 1];
            float w[8] = {w0.x, w0.y, w0.z, w0.w, w1.x, w1.y, w1.z, w1.w};
            bool asc = (((tid * 8) & k) == 0);
            cw(w[0],w[4],asc); cw(w[1],w[5],asc); cw(w[2],w[6],asc); cw(w[3],w[7],asc);
            cw(w[0],w[2],asc); cw(w[1],w[3],asc); cw(w[4],w[6],asc); cw(w[5],w[7],asc);
            cw(w[0],w[1],asc); cw(w[2],w[3],asc); cw(w[4],w[5],asc); cw(w[6],w[7],asc);
            reinterpret_cast<float4*>(sbuf)[2 * tid]     = make_float4(w[0], w[1], w[2], w[3]);
            reinterpret_cast<float4*>(sbuf)[2 * tid + 1] = make_float4(w[4], w[5], w[6], w[7]);
        }
    }
    __syncthreads();

    // ---- thread 0: combine scalars, compute all 20 features ----
    if (tid == 0) {
        float S1=0, S2=0, SD2=0, SAD=0, P1=0, P7=0, P24=0, SE1=0, SE2=0;
        float MN = red[9][0], MX = red[10][0];
        for (int w2 = 0; w2 < 4; w2++) {
            S1 += red[0][w2]; S2 += red[1][w2]; SD2 += red[2][w2]; SAD += red[3][w2];
            P1 += red[4][w2]; P7 += red[5][w2]; P24 += red[6][w2];
            SE1 += red[7][w2]; SE2 += red[8][w2];
            MN = fminf(MN, red[9][w2]); MX = fmaxf(MX, red[10][w2]);
        }
        float C2=0, C3=0, C4=0;
        for (int w2 = 0; w2 < 4; w2++) { C2 += redB[0][w2]; C3 += redB[1][w2]; C4 += redB[2][w2]; }

        const float Sf = (float)S_LEN;
        float m2 = C2 / Sf, m3 = C3 / Sf, m4 = C4 / Sf;
        float stdv = sqrtf(m2);

        float x0 = row[0], xl = row[S_LEN - 1];
        const float nd = Sf - 1.0f;
        float dmean = (xl - x0) / nd;
        float dvar = SD2 / nd - dmean * dmean;
        float std_diff = sqrtf(fmaxf(dvar, 0.f));
        float trend = std_diff / (stdv + EPS);

        float acv[3];
        const int lags[3] = {1, 7, 24};
        const float Ps[3] = {P1, P7, P24};
        for (int q = 0; q < 3; q++) {
            int L = lags[q];
            float n = (float)(S_LEN - L);
            float head = 0, headq = 0, tail = 0, tailq = 0;
            for (int i2 = 0; i2 < L; i2++) {
                float hv = row[i2];             head += hv; headq += hv * hv;
                float tv = row[S_LEN - L + i2]; tail += tv; tailq += tv * tv;
            }
            float sa = S1 - tail, sb = S1 - head;
            float qa = S2 - tailq, qb = S2 - headq;
            float am = sa / n, bm = sb / n;
            float cov = Ps[q] / n - am * bm;
            float as_ = sqrtf(fmaxf(qa / n - am * am, 0.f));
            float bs_ = sqrtf(fmaxf(qb / n - bm * bm, 0.f));
            acv[q] = cov / (as_ * bs_);
        }

        float cv = stdv / (fabsf(mean) + EPS);
        const float n24 = (float)((S_LEN + 23) / 24);   // 86
        float sm = SE1 / n24;
        float svar = SE2 / n24 - sm * sm;
        float seasonal = svar / (m2 + EPS);
        float skew = m3 / (m2 * stdv);
        float kurt = m4 / (m2 * m2) - 3.f;

        float q511 = sbuf[511],  q512 = sbuf[512];
        float q1023 = sbuf[1023], q1024 = sbuf[1024];
        float q1535 = sbuf[1535], q1536 = sbuf[1536];
        float p25 = q511  + 0.75f * (q512  - q511);
        float med = 0.5f * (q1023 + q1024);
        float p75 = q1535 + 0.25f * (q1536 - q1535);
        float iqr = p75 - p25;

        feats[0]  = fin(mean);      feats[1]  = fin(stdv);
        feats[2]  = fin(MN);        feats[3]  = fin(MX);
        feats[4]  = fin(med);       feats[5]  = fin(trend);
        feats[6]  = fin(acv[0]);    feats[7]  = fin(acv[1]);
        feats[8]  = fin(acv[2]);    feats[9]  = fin(cv);
        feats[10] = fin(iqr);       feats[11] = fin(seasonal);
        feats[12] = fin(skew);      feats[13] = fin(kurt);
        feats[14] = Sf;             feats[15] = fin(SAD);
        feats[16] = fin(SAD / nd);  feats[17] = fin(std_diff);
        feats[18] = fin(p25);       feats[19] = fin(p75);
    }
    __syncthreads();

    // ---- fused MLP: 20 -> 64 (relu) -> 128 ----
    if (tid < 64) {
        float acc = b1[tid];
        #pragma unroll
        for (int k2 = 0; k2 < 20; k2++) acc += feats[k2] * W1[tid * 20 + k2];
        hbuf[tid] = fmaxf(acc, 0.f);
    }
    __syncthreads();
    if (tid < 128) {
        float acc = b2[tid];
        #pragma unroll
        for (int j2 = 0; j2 < 64; j2++) acc += hbuf[j2] * W2[tid * 64 + j2];
        out[rowi * 128 + tid] = acc;
    }
}

extern "C" void kernel_launch(void* const* d_in, const int* in_sizes, int n_in,
                              void* d_out, int out_size, void* d_ws, size_t ws_size,
                              hipStream_t stream) {
    const float* x  = (const float*)d_in[0];
    const float* W1 = (const float*)d_in[1];
    const float* b1 = (const float*)d_in[2];
    const float* W2 = (const float*)d_in[3];
    const float* b2 = (const float*)d_in[4];
    float* out = (float*)d_out;
    int B = in_sizes[0] / S_LEN;
    stat_feat_kernel<<<B, TPB, 0, stream>>>(x, W1, b1, W2, b2, out);
}

// Round 2
// 433.667 us; speedup vs baseline: 1.2382x; 1.2382x over previous
//
#include <hip/hip_runtime.h>
#include <cmath>

constexpr int S_LEN = 2048;
constexpr int TPB   = 256;
constexpr float EPS = 1e-8f;

__device__ __forceinline__ float fin(float v) { return isfinite(v) ? v : 0.0f; }

// monotonic float -> orderable uint
__device__ __forceinline__ unsigned f2o(float f) {
    unsigned u = __float_as_uint(f);
    return (u & 0x80000000u) ? ~u : (u | 0x80000000u);
}
__device__ __forceinline__ float o2f(unsigned u) {
    return __uint_as_float((u & 0x80000000u) ? (u ^ 0x80000000u) : ~u);
}

__global__ __launch_bounds__(TPB) void stat_feat_kernel(
    const float* __restrict__ x,
    const float* __restrict__ W1, const float* __restrict__ b1,
    const float* __restrict__ W2, const float* __restrict__ b2,
    float* __restrict__ out)
{
    __shared__ float row[S_LEN];
    __shared__ int   hist1[256];   // round-1 histogram (kept)
    __shared__ int   excl1[256];   // round-1 exclusive scan (kept)
    __shared__ int   hist[256];    // rounds 2-4 scratch histogram
    __shared__ int   wsum[4];
    __shared__ int   selS[3];      // selected bin, its exclusive count, its size
    __shared__ unsigned uminS[4];
    __shared__ float red[11][4];
    __shared__ float redB[3][4];
    __shared__ float sc[1];
    __shared__ float feats[20];
    __shared__ float hbuf[64];
    __shared__ float qvals[6];     // v[511],v[512],v[1023],v[1024],v[1535],v[1536]

    const int tid  = threadIdx.x;
    const int lane = tid & 63;
    const int wv   = tid >> 6;
    const size_t rowi = blockIdx.x;

    // ---- load row: 8 contiguous floats per thread ----
    const float* xr = x + rowi * S_LEN;
    float4 a0 = reinterpret_cast<const float4*>(xr)[2 * tid];
    float4 a1 = reinterpret_cast<const float4*>(xr)[2 * tid + 1];
    float r0[8] = {a0.x, a0.y, a0.z, a0.w, a1.x, a1.y, a1.z, a1.w};
    reinterpret_cast<float4*>(row)[2 * tid]     = a0;
    reinterpret_cast<float4*>(row)[2 * tid + 1] = a1;
    __syncthreads();

    // ---- phase A: mean-independent accumulators ----
    float s1 = 0.f, s2 = 0.f, sd2 = 0.f, sad = 0.f;
    float p1 = 0.f, p7 = 0.f, p24 = 0.f, se1 = 0.f, se2 = 0.f;
    float mn = r0[0], mx = r0[0];
    const int base = tid * 8;
    #pragma unroll
    for (int e = 0; e < 8; e++) {
        float v = r0[e];
        int i = base + e;
        s1 += v; s2 += v * v;
        mn = fminf(mn, v); mx = fmaxf(mx, v);
        if (i % 24 == 0) { se1 += v; se2 += v * v; }
        if (i < S_LEN - 1) {
            float nx = (e < 7) ? r0[e + 1] : row[i + 1];
            float d = nx - v;
            sd2 += d * d; sad += fabsf(d); p1 += v * nx;
        }
        if (i < S_LEN - 7)  p7  += v * row[i + 7];
        if (i < S_LEN - 24) p24 += v * row[i + 24];
    }
    #pragma unroll
    for (int o = 32; o > 0; o >>= 1) {
        s1  += __shfl_down(s1,  o, 64);  s2  += __shfl_down(s2,  o, 64);
        sd2 += __shfl_down(sd2, o, 64);  sad += __shfl_down(sad, o, 64);
        p1  += __shfl_down(p1,  o, 64);  p7  += __shfl_down(p7,  o, 64);
        p24 += __shfl_down(p24, o, 64);
        se1 += __shfl_down(se1, o, 64);  se2 += __shfl_down(se2, o, 64);
        mn = fminf(mn, __shfl_down(mn, o, 64));
        mx = fmaxf(mx, __shfl_down(mx, o, 64));
    }
    if (lane == 0) {
        red[0][wv] = s1;  red[1][wv] = s2;  red[2][wv] = sd2; red[3][wv] = sad;
        red[4][wv] = p1;  red[5][wv] = p7;  red[6][wv] = p24;
        red[7][wv] = se1; red[8][wv] = se2;
        red[9][wv] = mn;  red[10][wv] = mx;
    }
    __syncthreads();
    if (tid == 0) {
        float t = red[0][0] + red[0][1] + red[0][2] + red[0][3];
        sc[0] = t * (1.0f / S_LEN);
    }
    __syncthreads();

    // ---- phase B: central moments (two-pass for accuracy) ----
    const float mean = sc[0];
    float c2 = 0.f, c3 = 0.f, c4 = 0.f;
    #pragma unroll
    for (int e = 0; e < 8; e++) {
        float xc = r0[e] - mean;
        float q = xc * xc;
        c2 += q; c3 += q * xc; c4 += q * q;
    }
    #pragma unroll
    for (int o = 32; o > 0; o >>= 1) {
        c2 += __shfl_down(c2, o, 64);
        c3 += __shfl_down(c3, o, 64);
        c4 += __shfl_down(c4, o, 64);
    }
    if (lane == 0) { redB[0][wv] = c2; redB[1][wv] = c3; redB[2][wv] = c4; }

    // ---- radix select: ranks 511/1023/1535 (+ successor each) ----
    unsigned u[8];
    #pragma unroll
    for (int e = 0; e < 8; e++) u[e] = f2o(r0[e]);

    // round 1 (top byte), shared by all three descents
    hist1[tid] = 0;
    __syncthreads();
    #pragma unroll
    for (int e = 0; e < 8; e++) atomicAdd(&hist1[u[e] >> 24], 1);
    __syncthreads();
    {
        int v = hist1[tid];
        int inc = v;
        #pragma unroll
        for (int o = 1; o < 64; o <<= 1) {
            int t = __shfl_up(inc, o, 64);
            if (lane >= o) inc += t;
        }
        if (lane == 63) wsum[wv] = inc;
        __syncthreads();
        int off = 0;
        for (int w = 0; w < wv; w++) off += wsum[w];
        excl1[tid] = off + inc - v;
    }
    __syncthreads();

    const int Ktar[3] = {511, 1023, 1535};
    for (int p = 0; p < 3; p++) {
        int K = Ktar[p];
        // round-1 bin selection from stored scan
        if (excl1[tid] <= K && K < excl1[tid] + hist1[tid]) {
            selS[0] = tid; selS[1] = excl1[tid]; selS[2] = hist1[tid];
        }
        __syncthreads();
        unsigned prefix = (unsigned)selS[0] << 24;
        int gLess = selS[1];
        int eqCnt = selS[2];
        K -= selS[1];
        __syncthreads();

        for (int s = 16; s >= 0; s -= 8) {
            hist[tid] = 0;
            __syncthreads();
            unsigned pref_hi = prefix >> (s + 8);
            #pragma unroll
            for (int e = 0; e < 8; e++) {
                if ((u[e] >> (s + 8)) == pref_hi)
                    atomicAdd(&hist[(u[e] >> s) & 255], 1);
            }
            __syncthreads();
            int v = hist[tid];
            int inc = v;
            #pragma unroll
            for (int o = 1; o < 64; o <<= 1) {
                int t = __shfl_up(inc, o, 64);
                if (lane >= o) inc += t;
            }
            if (lane == 63) wsum[wv] = inc;
            __syncthreads();
            int off = 0;
            for (int w = 0; w < wv; w++) off += wsum[w];
            int excl = off + inc - v;
            if (excl <= K && K < excl + v) {
                selS[0] = tid; selS[1] = excl; selS[2] = v;
            }
            __syncthreads();
            prefix |= (unsigned)selS[0] << s;
            gLess += selS[1];
            eqCnt  = selS[2];
            K     -= selS[1];
            __syncthreads();
        }

        const unsigned uK = prefix;  // exact bits of rank-K value
        // successor: min over u > uK (needed iff no tie extends past K)
        unsigned m = 0xFFFFFFFFu;
        #pragma unroll
        for (int e = 0; e < 8; e++)
            if (u[e] > uK) m = min(m, u[e]);
        #pragma unroll
        for (int o = 32; o > 0; o >>= 1)
            m = min(m, (unsigned)__shfl_down((int)m, o, 64));
        if (lane == 0) uminS[wv] = m;
        __syncthreads();
        if (tid == 0) {
            unsigned mm = min(min(uminS[0], uminS[1]), min(uminS[2], uminS[3]));
            bool same = (gLess + eqCnt) > (Ktar[p] + 1);
            float vK  = o2f(uK);
            qvals[2 * p]     = vK;
            qvals[2 * p + 1] = same ? vK : o2f(mm);
        }
        __syncthreads();
    }

    // ---- thread 0: combine scalars, compute all 20 features ----
    if (tid == 0) {
        float S1=0, S2=0, SD2=0, SAD=0, P1=0, P7=0, P24=0, SE1=0, SE2=0;
        float MN = red[9][0], MX = red[10][0];
        for (int w2 = 0; w2 < 4; w2++) {
            S1 += red[0][w2]; S2 += red[1][w2]; SD2 += red[2][w2]; SAD += red[3][w2];
            P1 += red[4][w2]; P7 += red[5][w2]; P24 += red[6][w2];
            SE1 += red[7][w2]; SE2 += red[8][w2];
            MN = fminf(MN, red[9][w2]); MX = fmaxf(MX, red[10][w2]);
        }
        float C2=0, C3=0, C4=0;
        for (int w2 = 0; w2 < 4; w2++) { C2 += redB[0][w2]; C3 += redB[1][w2]; C4 += redB[2][w2]; }

        const float Sf = (float)S_LEN;
        float m2 = C2 / Sf, m3 = C3 / Sf, m4 = C4 / Sf;
        float stdv = sqrtf(m2);

        float x0 = row[0], xl = row[S_LEN - 1];
        const float nd = Sf - 1.0f;
        float dmean = (xl - x0) / nd;
        float dvar = SD2 / nd - dmean * dmean;
        float std_diff = sqrtf(fmaxf(dvar, 0.f));
        float trend = std_diff / (stdv + EPS);

        float acv[3];
        const int lags[3] = {1, 7, 24};
        const float Ps[3] = {P1, P7, P24};
        for (int q = 0; q < 3; q++) {
            int L = lags[q];
            float n = (float)(S_LEN - L);
            float head = 0, headq = 0, tail = 0, tailq = 0;
            for (int i2 = 0; i2 < L; i2++) {
                float hv = row[i2];             head += hv; headq += hv * hv;
                float tv = row[S_LEN - L + i2]; tail += tv; tailq += tv * tv;
            }
            float sa = S1 - tail, sb = S1 - head;
            float qa = S2 - tailq, qb = S2 - headq;
            float am = sa / n, bm = sb / n;
            float cov = Ps[q] / n - am * bm;
            float as_ = sqrtf(fmaxf(qa / n - am * am, 0.f));
            float bs_ = sqrtf(fmaxf(qb / n - bm * bm, 0.f));
            acv[q] = cov / (as_ * bs_);
        }

        float cv = stdv / (fabsf(mean) + EPS);
        const float n24 = (float)((S_LEN + 23) / 24);   // 86
        float sm = SE1 / n24;
        float svar = SE2 / n24 - sm * sm;
        float seasonal = svar / (m2 + EPS);
        float skew = m3 / (m2 * stdv);
        float kurt = m4 / (m2 * m2) - 3.f;

        float p25 = qvals[0] + 0.75f * (qvals[1] - qvals[0]);
        float med = 0.5f * (qvals[2] + qvals[3]);
        float p75 = qvals[4] + 0.25f * (qvals[5] - qvals[4]);
        float iqr = p75 - p25;

        feats[0]  = fin(mean);      feats[1]  = fin(stdv);
        feats[2]  = fin(MN);        feats[3]  = fin(MX);
        feats[4]  = fin(med);       feats[5]  = fin(trend);
        feats[6]  = fin(acv[0]);    feats[7]  = fin(acv[1]);
        feats[8]  = fin(acv[2]);    feats[9]  = fin(cv);
        feats[10] = fin(iqr);       feats[11] = fin(seasonal);
        feats[12] = fin(skew);      feats[13] = fin(kurt);
        feats[14] = Sf;             feats[15] = fin(SAD);
        feats[16] = fin(SAD / nd);  feats[17] = fin(std_diff);
        feats[18] = fin(p25);       feats[19] = fin(p75);
    }
    __syncthreads();

    // ---- fused MLP: 20 -> 64 (relu) -> 128 ----
    if (tid < 64) {
        float acc = b1[tid];
        #pragma unroll
        for (int k2 = 0; k2 < 20; k2++) acc += feats[k2] * W1[tid * 20 + k2];
        hbuf[tid] = fmaxf(acc, 0.f);
    }
    __syncthreads();
    if (tid < 128) {
        float acc = b2[tid];
        #pragma unroll
        for (int j2 = 0; j2 < 64; j2++) acc += hbuf[j2] * W2[tid * 64 + j2];
        out[rowi * 128 + tid] = acc;
    }
}

extern "C" void kernel_launch(void* const* d_in, const int* in_sizes, int n_in,
                              void* d_out, int out_size, void* d_ws, size_t ws_size,
                              hipStream_t stream) {
    const float* x  = (const float*)d_in[0];
    const float* W1 = (const float*)d_in[1];
    const float* b1 = (const float*)d_in[2];
    const float* W2 = (const float*)d_in[3];
    const float* b2 = (const float*)d_in[4];
    float* out = (float*)d_out;
    int B = in_sizes[0] / S_LEN;
    stat_feat_kernel<<<B, TPB, 0, stream>>>(x, W1, b1, W2, b2, out);
}

// Round 3
// 328.235 us; speedup vs baseline: 1.6359x; 1.3212x over previous
//
#include <hip/hip_runtime.h>
#include <cmath>

constexpr int S_LEN = 2048;
constexpr float EPS = 1e-8f;

__device__ __forceinline__ float fin(float v) { return isfinite(v) ? v : 0.0f; }

// monotonic float -> orderable uint
__device__ __forceinline__ unsigned f2o(float f) {
    unsigned u = __float_as_uint(f);
    return (u & 0x80000000u) ? ~u : (u | 0x80000000u);
}
__device__ __forceinline__ float o2f(unsigned u) {
    return __uint_as_float((u & 0x80000000u) ? (u ^ 0x80000000u) : ~u);
}

__device__ __forceinline__ float wred_add(float v) {
    #pragma unroll
    for (int m = 1; m < 64; m <<= 1) v += __shfl_xor(v, m, 64);
    return v;
}
__device__ __forceinline__ float wred_min(float v) {
    #pragma unroll
    for (int m = 1; m < 64; m <<= 1) v = fminf(v, __shfl_xor(v, m, 64));
    return v;
}
__device__ __forceinline__ float wred_max(float v) {
    #pragma unroll
    for (int m = 1; m < 64; m <<= 1) v = fmaxf(v, __shfl_xor(v, m, 64));
    return v;
}
__device__ __forceinline__ unsigned wred_umin(unsigned v) {
    #pragma unroll
    for (int m = 1; m < 64; m <<= 1) {
        unsigned o = (unsigned)__shfl_xor((int)v, m, 64);
        v = v < o ? v : o;
    }
    return v;
}
// full-wave int sum on the VALU pipe (DPP), uniform result via readlane
__device__ __forceinline__ int wred_add_dpp(int v) {
    v += __builtin_amdgcn_update_dpp(0, v, 0xB1, 0xF, 0xF, true);  // quad_perm [1,0,3,2]
    v += __builtin_amdgcn_update_dpp(0, v, 0x4E, 0xF, 0xF, true);  // quad_perm [2,3,0,1]
    v += __builtin_amdgcn_update_dpp(0, v, 0x114, 0xF, 0xF, true); // row_shr:4
    v += __builtin_amdgcn_update_dpp(0, v, 0x118, 0xF, 0xF, true); // row_shr:8
    v += __builtin_amdgcn_update_dpp(0, v, 0x142, 0xA, 0xF, true); // row_bcast:15 -> rows 1,3
    v += __builtin_amdgcn_update_dpp(0, v, 0x143, 0xC, 0xF, true); // row_bcast:31 -> rows 2,3
    return __builtin_amdgcn_readlane(v, 63);
}

// Hacker's Delight 32x32 bit transpose (anti-diagonal orientation):
// after, bit-plane for value-bit b lives at A[31-b] (element e at mask bit 31-e).
__device__ __forceinline__ void transpose32(unsigned A[32]) {
    #pragma unroll
    for (int j = 16; j; j >>= 1) {
        unsigned m = (j == 16) ? 0x0000FFFFu : (j == 8) ? 0x00FF00FFu
                   : (j == 4) ? 0x0F0F0F0Fu : (j == 2) ? 0x33333333u : 0x55555555u;
        #pragma unroll
        for (int k = 0; k < 32; k++) {
            if (!(k & j)) {
                unsigned t = (A[k] ^ (A[k | j] >> j)) & m;
                A[k] ^= t;
                A[k | j] ^= (t << j);
            }
        }
    }
}

__global__ __launch_bounds__(256, 4) void stat_feat_kernel(
    const float* __restrict__ x,
    const float* __restrict__ W1, const float* __restrict__ b1,
    const float* __restrict__ W2, const float* __restrict__ b2,
    float* __restrict__ out, int nrows)
{
    __shared__ float w2s[128 * 65];  // 33280 B, +65 pad: conflict-free j-varying reads
    __shared__ float w1s[64 * 21];   // 5376 B
    __shared__ float featss[4 * 20]; // 320 B
    __shared__ float hs[4 * 64];     // 1024 B   => 40000 B total -> 4 blocks/CU

    const int tid  = threadIdx.x;
    const int lane = tid & 63;
    const int w    = tid >> 6;
    const int row  = min(blockIdx.x * 4 + w, nrows - 1);

    // ---- stage weights coalesced into LDS ----
    for (int n = tid; n < 64 * 20; n += 256) w1s[(n / 20) * 21 + (n % 20)] = W1[n];
    #pragma unroll
    for (int it = 0; it < 32; it++) {
        int n = tid + 256 * it;
        w2s[(n >> 6) * 65 + (n & 63)] = W2[n];
    }

    // ---- load row: 32 contiguous floats per lane ----
    float v[32];
    const float* xr = x + (size_t)row * S_LEN + lane * 32;
    #pragma unroll
    for (int q = 0; q < 8; q++) {
        float4 t = reinterpret_cast<const float4*>(xr)[q];
        v[4 * q + 0] = t.x; v[4 * q + 1] = t.y; v[4 * q + 2] = t.z; v[4 * q + 3] = t.w;
    }

    // ---- phase A: streaming accumulators (in-register) ----
    float s1 = 0.f, s2 = 0.f, sd2 = 0.f, sad = 0.f;
    float p1 = 0.f, p7 = 0.f, p24 = 0.f, se1 = 0.f, se2 = 0.f;
    float mn = v[0], mx = v[0];
    #pragma unroll
    for (int e = 0; e < 32; e++) {
        float val = v[e];
        s1 += val; s2 = fmaf(val, val, s2);
        mn = fminf(mn, val); mx = fmaxf(mx, val);
    }
    #pragma unroll
    for (int e = 0; e < 31; e++) {
        float d = v[e + 1] - v[e];
        sd2 = fmaf(d, d, sd2); sad += fabsf(d);
        p1 = fmaf(v[e], v[e + 1], p1);
    }
    #pragma unroll
    for (int e = 0; e < 25; e++) p7 = fmaf(v[e], v[e + 7], p7);
    #pragma unroll
    for (int e = 0; e < 8; e++)  p24 = fmaf(v[e], v[e + 24], p24);

    const bool notlast = (lane < 63);
    #pragma unroll
    for (int j = 0; j < 24; j++) {
        float nb = __shfl_down(v[j], 1, 64);      // next lane's v[j] (shuffle on all lanes)
        float g = notlast ? nb : 0.f;
        p24 = fmaf(v[8 + j], g, p24);             // e = 8+j pairs with x[i+24]
        if (j < 7) p7 = fmaf(v[25 + j], g, p7);   // e = 25+j pairs with x[i+7]
        if (j == 0 && notlast) {                  // e = 31 pairs with x[i+1]
            float d = nb - v[31];
            sd2 = fmaf(d, d, sd2); sad += fabsf(d);
            p1 = fmaf(v[31], nb, p1);
        }
    }
    // seasonal x[::24]: i = 32*lane + e == 0 (mod 24)  <=>  lane%3 pattern
    {
        int r3 = lane % 3;
        float sv = (r3 == 0) ? v[0] : ((r3 == 1) ? v[16] : v[8]);
        se1 += sv; se2 = fmaf(sv, sv, se2);
        if (r3 == 0) { se1 += v[24]; se2 = fmaf(v[24], v[24], se2); }
    }
    // head/tail partial sums for autocorr edge corrections (lanes 0 / 63 own them)
    float h1 = 0, h7 = 0, h24 = 0, hq1 = 0, hq7 = 0, hq24 = 0;
    float t1 = 0, t7 = 0, t24 = 0, tq1 = 0, tq7 = 0, tq24 = 0;
    if (lane == 0) {
        h1 = v[0]; hq1 = v[0] * v[0];
        float a = 0, b = 0;
        #pragma unroll
        for (int i = 0; i < 7; i++) { a += v[i]; b = fmaf(v[i], v[i], b); }
        h7 = a; hq7 = b;
        #pragma unroll
        for (int i = 7; i < 24; i++) { a += v[i]; b = fmaf(v[i], v[i], b); }
        h24 = a; hq24 = b;
    }
    if (lane == 63) {
        t1 = v[31]; tq1 = v[31] * v[31];
        float a = 0, b = 0;
        #pragma unroll
        for (int i = 25; i < 32; i++) { a += v[i]; b = fmaf(v[i], v[i], b); }
        t7 = a; tq7 = b;
        a = 0; b = 0;
        #pragma unroll
        for (int i = 8; i < 32; i++) { a += v[i]; b = fmaf(v[i], v[i], b); }
        t24 = a; tq24 = b;
    }
    h1 = __shfl(h1, 0, 64);   hq1 = __shfl(hq1, 0, 64);
    h7 = __shfl(h7, 0, 64);   hq7 = __shfl(hq7, 0, 64);
    h24 = __shfl(h24, 0, 64); hq24 = __shfl(hq24, 0, 64);
    t1 = __shfl(t1, 63, 64);  tq1 = __shfl(tq1, 63, 64);
    t7 = __shfl(t7, 63, 64);  tq7 = __shfl(tq7, 63, 64);
    t24 = __shfl(t24, 63, 64); tq24 = __shfl(tq24, 63, 64);

    // ---- wave reductions (butterfly -> uniform on all lanes) ----
    float S1  = wred_add(s1);
    float mean = S1 * (1.0f / S_LEN);
    float S2  = wred_add(s2);
    float SD2 = wred_add(sd2);
    float SAD = wred_add(sad);
    float P1  = wred_add(p1);
    float P7  = wred_add(p7);
    float P24 = wred_add(p24);
    float SE1 = wred_add(se1);
    float SE2 = wred_add(se2);
    float MN  = wred_min(mn);
    float MX  = wred_max(mx);

    // ---- phase B: central moments (two-pass) ----
    float c2 = 0.f, c3 = 0.f, c4 = 0.f;
    #pragma unroll
    for (int e = 0; e < 32; e++) {
        float xc = v[e] - mean;
        float q = xc * xc;
        c2 += q; c3 = fmaf(q, xc, c3); c4 = fmaf(q, q, c4);
    }
    float C2 = wred_add(c2), C3 = wred_add(c3), C4 = wred_add(c4);

    // ---- bit-plane radix select for ranks 511/1023/1535 (+ successors) ----
    unsigned u[32];
    #pragma unroll
    for (int e = 0; e < 32; e++) u[e] = f2o(v[e]);
    unsigned msk[32];
    #pragma unroll
    for (int e = 0; e < 32; e++) msk[e] = u[e];
    transpose32(msk);

    unsigned act0 = ~0u, act1 = ~0u, act2 = ~0u;
    int K0 = 511, K1 = 1023, K2 = 1535;
    unsigned uK0 = 0, uK1 = 0, uK2 = 0;
    #pragma unroll
    for (int b = 31; b >= 0; b--) {
        unsigned mb = msk[31 - b];
        unsigned z0 = act0 & ~mb, z1 = act1 & ~mb, z2 = act2 & ~mb;
        int C01 = wred_add_dpp(__popc(z0) | (__popc(z1) << 16));
        int Cc2 = wred_add_dpp(__popc(z2));
        int c0 = C01 & 0xFFFF;
        int c1 = (int)((unsigned)C01 >> 16);
        if (K0 < c0)  act0 = z0; else { K0 -= c0;  act0 &= mb; uK0 |= (1u << b); }
        if (K1 < c1)  act1 = z1; else { K1 -= c1;  act1 &= mb; uK1 |= (1u << b); }
        if (K2 < Cc2) act2 = z2; else { K2 -= Cc2; act2 &= mb; uK2 |= (1u << b); }
    }
    int e01 = wred_add_dpp(__popc(act0) | (__popc(act1) << 16));
    int eq0 = e01 & 0xFFFF, eq1 = (int)((unsigned)e01 >> 16);
    int eq2 = wred_add_dpp(__popc(act2));
    unsigned m0 = ~0u, m1 = ~0u, m2 = ~0u;
    #pragma unroll
    for (int e = 0; e < 32; e++) {
        unsigned ue = u[e];
        if (ue > uK0) m0 = m0 < ue ? m0 : ue;
        if (ue > uK1) m1 = m1 < ue ? m1 : ue;
        if (ue > uK2) m2 = m2 < ue ? m2 : ue;
    }
    m0 = wred_umin(m0); m1 = wred_umin(m1); m2 = wred_umin(m2);
    float v511 = o2f(uK0), v1023 = o2f(uK1), v1535 = o2f(uK2);
    float v512  = (K0 + 1 < eq0) ? v511  : o2f(m0);  // K now = rank within equal-class
    float v1024 = (K1 + 1 < eq1) ? v1023 : o2f(m1);
    float v1536 = (K2 + 1 < eq2) ? v1535 : o2f(m2);

    // ---- features (wave-uniform, computed redundantly on all lanes) ----
    const float Sf = (float)S_LEN;
    const float nd = Sf - 1.0f;
    float m2v = C2 / Sf, m3v = C3 / Sf, m4v = C4 / Sf;
    float stdv = sqrtf(m2v);
    float dmean = (t1 - h1) / nd;                  // (x_last - x_first)/(S-1)
    float dvar = SD2 / nd - dmean * dmean;
    float std_diff = sqrtf(fmaxf(dvar, 0.f));
    float trend = std_diff / (stdv + EPS);

    float ac[3];
    {
        const float Ls[3] = {1.f, 7.f, 24.f};
        const float Ps[3] = {P1, P7, P24};
        const float hd[3] = {h1, h7, h24},   hq[3] = {hq1, hq7, hq24};
        const float tl[3] = {t1, t7, t24},   tq[3] = {tq1, tq7, tq24};
        #pragma unroll
        for (int q = 0; q < 3; q++) {
            float n = Sf - Ls[q];
            float sa = S1 - tl[q], sb = S1 - hd[q];
            float qa = S2 - tq[q], qb = S2 - hq[q];
            float am = sa / n, bm = sb / n;
            float cov = Ps[q] / n - am * bm;
            float as_ = sqrtf(fmaxf(qa / n - am * am, 0.f));
            float bs_ = sqrtf(fmaxf(qb / n - bm * bm, 0.f));
            ac[q] = cov / (as_ * bs_);
        }
    }
    float cv = stdv / (fabsf(mean) + EPS);
    float sm = SE1 / 86.f;
    float svar = SE2 / 86.f - sm * sm;
    float seasonal = svar / (m2v + EPS);
    float skew = m3v / (m2v * stdv);
    float kurt = m4v / (m2v * m2v) - 3.f;
    float p25 = v511 + 0.75f * (v512 - v511);
    float med = 0.5f * (v1023 + v1024);
    float p75 = v1535 + 0.25f * (v1536 - v1535);
    float iqr = p75 - p25;

    if (lane == 0) {
        float* fp = &featss[w * 20];
        fp[0] = fin(mean);     fp[1] = fin(stdv);
        fp[2] = fin(MN);       fp[3] = fin(MX);
        fp[4] = fin(med);      fp[5] = fin(trend);
        fp[6] = fin(ac[0]);    fp[7] = fin(ac[1]);
        fp[8] = fin(ac[2]);    fp[9] = fin(cv);
        fp[10] = fin(iqr);     fp[11] = fin(seasonal);
        fp[12] = fin(skew);    fp[13] = fin(kurt);
        fp[14] = Sf;           fp[15] = fin(SAD);
        fp[16] = fin(SAD / nd); fp[17] = fin(std_diff);
        fp[18] = fin(p25);     fp[19] = fin(p75);
    }
    __syncthreads();

    // ---- fused MLP (block-level): h = relu(feats @ W1^T + b1) ----
    {
        float acc = b1[lane];
        #pragma unroll
        for (int j = 0; j < 20; j++)
            acc = fmaf(featss[w * 20 + j], w1s[lane * 21 + j], acc);
        hs[w * 64 + lane] = fmaxf(acc, 0.f);
    }
    __syncthreads();
    // ---- out = h @ W2^T + b2 : thread -> (j, rows r0 & r0+2) ----
    {
        int j  = tid & 127;
        int r0 = tid >> 7;
        int r1 = r0 + 2;
        float acc0 = b2[j], acc1 = acc0;
        #pragma unroll
        for (int k = 0; k < 64; k++) {
            float wv2 = w2s[j * 65 + k];
            acc0 = fmaf(hs[r0 * 64 + k], wv2, acc0);
            acc1 = fmaf(hs[r1 * 64 + k], wv2, acc1);
        }
        size_t rb = (size_t)blockIdx.x * 4;
        size_t o0 = (rb + r0) * 128 + j;
        size_t o1 = (rb + r1) * 128 + j;
        if ((int)(rb + r0) < nrows) out[o0] = acc0;
        if ((int)(rb + r1) < nrows) out[o1] = acc1;
    }
}

extern "C" void kernel_launch(void* const* d_in, const int* in_sizes, int n_in,
                              void* d_out, int out_size, void* d_ws, size_t ws_size,
                              hipStream_t stream) {
    const float* x  = (const float*)d_in[0];
    const float* W1 = (const float*)d_in[1];
    const float* b1 = (const float*)d_in[2];
    const float* W2 = (const float*)d_in[3];
    const float* b2 = (const float*)d_in[4];
    float* out = (float*)d_out;
    int nrows = in_sizes[0] / S_LEN;
    int blocks = (nrows + 3) / 4;
    stat_feat_kernel<<<blocks, 256, 0, stream>>>(x, W1, b1, W2, b2, out, nrows);
}